// Round 3
// baseline (297.748 us; speedup 1.0000x reference)
//
#include <hip/hip_runtime.h>
#include <hip/hip_bf16.h>
#include <cstdint>

#define BATCH 4096
#define LAT   2048
#define NFREQ 2074
#define KPAD  2112   // NFREQ padded up to a multiple of 64 (zero-filled)

typedef __bf16 bf16x8 __attribute__((ext_vector_type(8)));
typedef float  f32x4  __attribute__((ext_vector_type(4)));

__device__ __forceinline__ unsigned short f2bf(float f) {
    unsigned int u = __float_as_uint(f);
    u = (u + 0x7fffu + ((u >> 16) & 1u)) >> 16;
    return (unsigned short)u;
}

__device__ __forceinline__ void gload_lds16(const unsigned short* g, unsigned short* l) {
    __builtin_amdgcn_global_load_lds(
        (const __attribute__((address_space(1))) unsigned int*)g,
        (__attribute__((address_space(3))) unsigned int*)l,
        16, 0, 0);
}

// ---------------------------------------------------------------------------
// LDS chunk layout (slot-swizzled, conflict-free):
// A "chunk" = 16 rows x 32 k of bf16 = 1024 B, written by one gload_lds16
// (lane L -> physical slot L*16B). Lane L FETCHES row (L&15), k-quad (L>>4),
// so physical slot s holds (row = s&15, kq = s>>4). The MFMA fragment read
// for (row=l16, kq=quad) is slot quad*16+l16 -> start bank 4*l16 mod 32 ->
// exactly 2 lanes per 4-bank group (2-way aliasing is free, m136).
// ---------------------------------------------------------------------------

// prep: blocks [0,4096)    -> cast x fp32 -> bf16 (8 elem/thread) + init max
//       blocks [4096,5152) -> transpose+cast W  -> WT  [LAT][KPAD]
//       blocks [5152,6208) -> transpose+cast cb -> cosT[LAT][KPAD]
__global__ void prep_kernel(const float* __restrict__ x,
                            const float* __restrict__ W,
                            const float* __restrict__ cb,
                            unsigned short* __restrict__ xb,
                            unsigned short* __restrict__ WT,
                            unsigned short* __restrict__ cosT,
                            float* __restrict__ maxp) {
    __shared__ float t[64][65];
    const int bid = blockIdx.x;
    const int tid = threadIdx.x;
    if (bid < 4096) {
        int i = bid * 256 + tid;
        const float4* x4 = (const float4*)x;
        float4 a = x4[2 * i];
        float4 b = x4[2 * i + 1];
        union { unsigned short us[8]; uint4 v; } p;
        p.us[0] = f2bf(a.x); p.us[1] = f2bf(a.y); p.us[2] = f2bf(a.z); p.us[3] = f2bf(a.w);
        p.us[4] = f2bf(b.x); p.us[5] = f2bf(b.y); p.us[6] = f2bf(b.z); p.us[7] = f2bf(b.w);
        ((uint4*)xb)[i] = p.v;
        if (i == 0) *maxp = -__builtin_inff();
        return;
    }
    int b2 = bid - 4096;
    const float* in     = (b2 < 1056) ? W  : cb;
    unsigned short* out = (b2 < 1056) ? WT : cosT;
    if (b2 >= 1056) b2 -= 1056;
    const int c0 = (b2 % 32) * 64;
    const int r0 = (b2 / 32) * 64;
    for (int i = tid; i < 4096; i += 256) {
        int rr = i >> 6, cc = i & 63;
        int r = r0 + rr;
        float v = (r < NFREQ) ? in[(size_t)r * LAT + c0 + cc] : 0.0f;
        t[rr][cc] = v;
    }
    __syncthreads();
    for (int i = tid; i < 4096; i += 256) {
        int cc = i >> 6, rr = i & 63;
        out[(size_t)(c0 + cc) * KPAD + (r0 + rr)] = f2bf(t[rr][cc]);
    }
}

// ---------------------------------------------------------------------------
// GEMM1: C[m][n] = sum_k A[m][k]*Bt[n][k], bf16 out.
// 64x64 block = ONE wave (no barriers!), 3-stage circular LDS, 2-deep vmcnt
// prefetch. WAR safety by program order: reads of buffer (j+2)%3 happened at
// iter j-1... (= (j-1)%3) and were lgkm-completed before MFMA(j-1), which
// precedes the iter-j DMA issue in this single wave's program order.
template <int N, int K>
__global__ __launch_bounds__(64, 2)
void gemm1_kernel(const unsigned short* __restrict__ A,
                  const unsigned short* __restrict__ Bt,
                  unsigned short* __restrict__ C) {
    __shared__ alignas(16) unsigned short As[3][4 * 512];
    __shared__ alignas(16) unsigned short Bs[3][4 * 512];
    const int lane = threadIdx.x;
    const int quad = lane >> 4, l16 = lane & 15;
    const int mBase = blockIdx.y * 64, nBase = blockIdx.x * 64;
    const int sk = quad * 8;

    const unsigned short* Ag[4];
    const unsigned short* Bg[4];
#pragma unroll
    for (int c = 0; c < 4; ++c) {
        Ag[c] = A  + (size_t)(mBase + c * 16 + l16) * K + sk;
        Bg[c] = Bt + (size_t)(nBase + c * 16 + l16) * K + sk;
    }

    constexpr int NIT = K / 32;
    // prologue: tiles 0 and 1 into buffers 0 and 1
#pragma unroll
    for (int c = 0; c < 4; ++c) { gload_lds16(Ag[c], &As[0][c * 512]); }
#pragma unroll
    for (int c = 0; c < 4; ++c) { gload_lds16(Bg[c], &Bs[0][c * 512]); }
#pragma unroll
    for (int c = 0; c < 4; ++c) { gload_lds16(Ag[c] + 32, &As[1][c * 512]); }
#pragma unroll
    for (int c = 0; c < 4; ++c) { gload_lds16(Bg[c] + 32, &Bs[1][c * 512]); }

    f32x4 acc[4][4] = {};
    int bc = 0;
    for (int j = 0; j < NIT; ++j) {
        const int bw = (bc == 0) ? 2 : bc - 1;   // (j+2)%3
        if (j + 2 < NIT) {
            const int k0 = (j + 2) * 32;
#pragma unroll
            for (int c = 0; c < 4; ++c) gload_lds16(Ag[c] + k0, &As[bw][c * 512]);
#pragma unroll
            for (int c = 0; c < 4; ++c) gload_lds16(Bg[c] + k0, &Bs[bw][c * 512]);
            asm volatile("s_waitcnt vmcnt(16)" ::: "memory");
        } else if (j + 1 < NIT) {
            asm volatile("s_waitcnt vmcnt(8)" ::: "memory");
        } else {
            asm volatile("s_waitcnt vmcnt(0)" ::: "memory");
        }
        bf16x8 af[4], bfr[4];
#pragma unroll
        for (int c = 0; c < 4; ++c) {
            af[c]  = *(const bf16x8*)&As[bc][c * 512 + (quad * 16 + l16) * 8];
            bfr[c] = *(const bf16x8*)&Bs[bc][c * 512 + (quad * 16 + l16) * 8];
        }
#pragma unroll
        for (int mi = 0; mi < 4; ++mi)
#pragma unroll
            for (int ni = 0; ni < 4; ++ni)
                acc[mi][ni] = __builtin_amdgcn_mfma_f32_16x16x32_bf16(
                    af[mi], bfr[ni], acc[mi][ni], 0, 0, 0);
        bc = (bc == 2) ? 0 : bc + 1;
    }

    // C/D layout: col = lane&15, row = quad*4 + reg
#pragma unroll
    for (int mi = 0; mi < 4; ++mi)
#pragma unroll
        for (int ni = 0; ni < 4; ++ni) {
            int col = nBase + ni * 16 + l16;
#pragma unroll
            for (int r = 0; r < 4; ++r) {
                int row = mBase + mi * 16 + quad * 4 + r;
                C[(size_t)row * N + col] = f2bf(acc[mi][ni][r]);
            }
        }
}

// ---------------------------------------------------------------------------
// GEMM2: 128x64 block, 2 waves (each wave a 64x64 output tile), 3-stage
// circular LDS, one raw s_barrier per iter with vmcnt(6) straddle.
// fp32 out + global max via one atomic per wave.
template <int N, int K>
__global__ __launch_bounds__(128, 2)
void gemm2_kernel(const unsigned short* __restrict__ A,
                  const unsigned short* __restrict__ Bt,
                  float* __restrict__ C,
                  float* __restrict__ maxp) {
    __shared__ alignas(16) unsigned short As[3][8 * 512];
    __shared__ alignas(16) unsigned short Bs[3][4 * 512];
    const int tid  = threadIdx.x;
    const int wave = tid >> 6;
    const int lane = tid & 63;
    const int quad = lane >> 4, l16 = lane & 15;
    const int wm   = wave * 64;
    const int mBase = blockIdx.y * 128, nBase = blockIdx.x * 64;
    const int sk = quad * 8;

    // wave w stages As chunks [4w,4w+4) and Bs chunks [2w,2w+2)
    const unsigned short* Ag[4];
    const unsigned short* Bg[2];
#pragma unroll
    for (int c = 0; c < 4; ++c)
        Ag[c] = A + (size_t)(mBase + (wave * 4 + c) * 16 + l16) * K + sk;
#pragma unroll
    for (int c = 0; c < 2; ++c)
        Bg[c] = Bt + (size_t)(nBase + (wave * 2 + c) * 16 + l16) * K + sk;

    constexpr int NIT = K / 32;
    // prologue: tile 0 into buffer 0
#pragma unroll
    for (int c = 0; c < 4; ++c) gload_lds16(Ag[c], &As[0][(wave * 4 + c) * 512]);
#pragma unroll
    for (int c = 0; c < 2; ++c) gload_lds16(Bg[c], &Bs[0][(wave * 2 + c) * 512]);

    f32x4 acc[4][4] = {};
    int bc = 0;
    for (int j = 0; j < NIT; ++j) {
        const int bn = (bc == 2) ? 0 : bc + 1;
        if (j + 1 < NIT) {
            const int k0 = (j + 1) * 32;
#pragma unroll
            for (int c = 0; c < 4; ++c) gload_lds16(Ag[c] + k0, &As[bn][(wave * 4 + c) * 512]);
#pragma unroll
            for (int c = 0; c < 2; ++c) gload_lds16(Bg[c] + k0, &Bs[bn][(wave * 2 + c) * 512]);
            asm volatile("s_waitcnt vmcnt(6)\n\ts_barrier" ::: "memory");
        } else {
            asm volatile("s_waitcnt vmcnt(0)\n\ts_barrier" ::: "memory");
        }
        bf16x8 af[4], bfr[4];
#pragma unroll
        for (int mi = 0; mi < 4; ++mi)
            af[mi] = *(const bf16x8*)&As[bc][(wave * 4 + mi) * 512 + (quad * 16 + l16) * 8];
#pragma unroll
        for (int ni = 0; ni < 4; ++ni)
            bfr[ni] = *(const bf16x8*)&Bs[bc][ni * 512 + (quad * 16 + l16) * 8];
#pragma unroll
        for (int mi = 0; mi < 4; ++mi)
#pragma unroll
            for (int ni = 0; ni < 4; ++ni)
                acc[mi][ni] = __builtin_amdgcn_mfma_f32_16x16x32_bf16(
                    af[mi], bfr[ni], acc[mi][ni], 0, 0, 0);
        bc = bn;
    }

    // epilogue: fp32 store + global max
    float vmax = -__builtin_inff();
#pragma unroll
    for (int mi = 0; mi < 4; ++mi)
#pragma unroll
        for (int ni = 0; ni < 4; ++ni) {
            int col = nBase + ni * 16 + l16;
#pragma unroll
            for (int r = 0; r < 4; ++r) {
                int row = mBase + wm + mi * 16 + quad * 4 + r;
                float v = acc[mi][ni][r];
                C[(size_t)row * N + col] = v;
                vmax = fmaxf(vmax, v);
            }
        }
#pragma unroll
    for (int off = 32; off > 0; off >>= 1)
        vmax = fmaxf(vmax, __shfl_xor(vmax, off));
    if (lane == 0) {
        if (vmax >= 0.0f) atomicMax((int*)maxp, __float_as_int(vmax));
        else              atomicMin((unsigned int*)maxp, __float_as_uint(vmax));
    }
}

// ---------------------------------------------------------------------------
__global__ void scale_kernel(float* __restrict__ out, const float* __restrict__ maxp) {
    int i = blockIdx.x * blockDim.x + threadIdx.x;
    float inv = 1.0f / (*maxp);
    float4* o4 = (float4*)out;
    float4 v = o4[i];
    v.x *= inv; v.y *= inv; v.z *= inv; v.w *= inv;
    o4[i] = v;
}

// ---------------------------------------------------------------------------
extern "C" void kernel_launch(void* const* d_in, const int* in_sizes, int n_in,
                              void* d_out, int out_size, void* d_ws, size_t ws_size,
                              hipStream_t stream) {
    const float* x  = (const float*)d_in[0];  // (4096, 2048)
    const float* W  = (const float*)d_in[1];  // (2074, 2048)
    const float* cb = (const float*)d_in[2];  // (2074, 2048)

    char* ws = (char*)d_ws;
    unsigned short* xb   = (unsigned short*)ws;                               // [4096][2048] bf16
    unsigned short* WT   = (unsigned short*)(ws + (size_t)BATCH * LAT * 2);   // [2048][2112] bf16
    unsigned short* cosT = (unsigned short*)((char*)WT + (size_t)LAT * KPAD * 2);
    unsigned short* C1   = (unsigned short*)((char*)cosT + (size_t)LAT * KPAD * 2); // [2048][2048] bf16
    float*          maxp = (float*)((char*)C1 + (size_t)LAT * LAT * 2);
    float*          out  = (float*)d_out;

    // 1. fused prep: cast x -> bf16 (+init max), transpose+cast W and cos_basis
    prep_kernel<<<4096 + 2 * 1056, 256, 0, stream>>>(x, W, cb, xb, WT, cosT, maxp);

    // 2. C1[l2][l1] = sum_f cosT[l2,f] * WT[l1,f]  (single-wave 64x64 blocks)
    gemm1_kernel<LAT, KPAD>
        <<<dim3(LAT / 64, LAT / 64), 64, 0, stream>>>(cosT, WT, C1);

    // 3. out[b][l2] = sum_l1 xb[b][l1] * C1[l2][l1]  (128x64 blocks, 2 waves)
    gemm2_kernel<LAT, LAT>
        <<<dim3(LAT / 64, BATCH / 128), 128, 0, stream>>>(xb, C1, out, maxp);

    // 4. out /= max
    scale_kernel<<<(out_size / 4) / 256, 256, 0, stream>>>(out, maxp);
}